// Round 9
// baseline (214.949 us; speedup 1.0000x reference)
//
#include <hip/hip_runtime.h>

// uDTW forward DP, R8: 2 rows/thread, 256 threads (4 waves, 1 wave/SIMD).
// R7 was issue-bound: 2 waves/SIMD x ~1400 cyc/phase. Here thread t owns rows
// 2t (cell A) and 2t+1 (cell B). Cell B's upper neighbor is cell A of the SAME
// thread -> register operands, no dpp/cndmask for half the cells. 1 wave/SIMD
// removes co-issue contention; skew depth 3 -> 35 phases; 3 LDS boundaries.
// Cells A,B within a step are independent (both read only d-1/d-2 state).
// Row A window offsets always even, row B always odd -> one select stage each.
// ddL validity mask dropped: garbage D always multiplies a masked-zero E.
// Publish: all-lane write-once (lane 63's write provably temporally last).

constexpr int N = 512;
constexpr int M = 512;
constexpr int BATCH = 32;
constexpr int NM = 1024;                 // diags d = 2..NM
constexpr int K = 32;                    // diagonals per burst
constexpr int NB = 32;                   // bursts cover d = 2..1025
constexpr int PHASES = NB + 3;           // 35 (4 waves, skew 3)
constexpr int OFF = 128;                 // edge halo offset
constexpr int EW = 768;                  // edge row: cols -128..639
constexpr float NL2E = -1.4426950408889634f;   // -log2(e)
constexpr float NLN2 = -0.6931471805599453f;   // -ln(2)

__device__ __forceinline__ float lane_shr1(float x) {
  return __int_as_float(
      __builtin_amdgcn_update_dpp(0, __float_as_int(x), 0x138, 0xf, 0xf, true));
}
__device__ __forceinline__ int qclamp(int q) {
  return q < 0 ? 0 : (q > 127 ? 127 : q);
}

__global__ __launch_bounds__(256, 1)
void softdtw_fwd(const float* __restrict__ D,
                 const float* __restrict__ Sig,
                 float* __restrict__ out) {
  const int b = blockIdx.x;
  const int t = threadIdx.x;            // 0..255; rows 2t (A), 2t+1 (B)
  const int w = t >> 6;                 // wave 0..3
  const bool l0 = ((t & 63) == 0);
  const float4* DrowA = (const float4*)(D + ((size_t)b * N + 2 * t) * M);
  const float4* DrowB = DrowA + (M / 4);

  // edge[w][OFF + c] = (exp(-R), NL2E*D) of boundary row 128w+127 at column c
  __shared__ float2 edge[4][EW];
  for (int idx = t; idx < 4 * EW; idx += 256)
    ((float2*)edge)[idx] = make_float2(0.f, 0.f);

  // carried state at d-1 / d-2 (E = exp(-R); d* = NL2E*Dval)
  float eA = 0.f, dA = 0.f, eN2A = (t == 0) ? 1.f : 0.f, dN2A = 0.f;
  float eB = 0.f, dB = 0.f, eN2B = 0.f, dN2B = 0.f;

  // Sig enters only via 4 elements at the final cell (row 511 = t=255 cell B)
  float sgA = 0.f, sg0 = 0.f, sg1 = 0.f, sg2 = 0.f;
  if (t == 255) {
    const float* Sb = Sig + (size_t)b * N * M;
    sgA = Sb[(size_t)511 * 512 + 511];
    sg0 = Sb[(size_t)510 * 512 + 510];
    sg1 = Sb[(size_t)510 * 512 + 511];
    sg2 = Sb[(size_t)511 * 512 + 510];
  }

  const int Bl = 4 * w, Bh = 4 * w + 19;   // active bursts for this wave

  // current-burst D windows (9 quads per row)
  float4 rA0, rA1, rA2, rA3, rA4, rA5, rA6, rA7, rA8;
  float4 rB0, rB1, rB2, rB3, rB4, rB5, rB6, rB7, rB8;
  {
    const int qa = (32 * Bl - 2 * t) >> 2;
    const int qb = (32 * Bl - 2 * t - 1) >> 2;
    rA0 = DrowA[qclamp(qa + 0)]; rA1 = DrowA[qclamp(qa + 1)];
    rA2 = DrowA[qclamp(qa + 2)]; rA3 = DrowA[qclamp(qa + 3)];
    rA4 = DrowA[qclamp(qa + 4)]; rA5 = DrowA[qclamp(qa + 5)];
    rA6 = DrowA[qclamp(qa + 6)]; rA7 = DrowA[qclamp(qa + 7)];
    rA8 = DrowA[qclamp(qa + 8)];
    rB0 = DrowB[qclamp(qb + 0)]; rB1 = DrowB[qclamp(qb + 1)];
    rB2 = DrowB[qclamp(qb + 2)]; rB3 = DrowB[qclamp(qb + 3)];
    rB4 = DrowB[qclamp(qb + 4)]; rB5 = DrowB[qclamp(qb + 5)];
    rB6 = DrowB[qclamp(qb + 6)]; rB7 = DrowB[qclamp(qb + 7)];
    rB8 = DrowB[qclamp(qb + 8)];
  }
  __syncthreads();

  for (int p = 0; p < PHASES; ++p) {
    const int B = p - w;
    const int Bn = B + 1;
    const bool dopre = (Bn >= Bl) && (Bn <= Bh);

    // prefetch next burst's D windows (rotated in after the body)
    float4 pA0, pA1, pA2, pA3, pA4, pA5, pA6, pA7, pA8;
    float4 pB0, pB1, pB2, pB3, pB4, pB5, pB6, pB7, pB8;
    if (dopre) {
      const int qa = (32 * Bn - 2 * t) >> 2;
      const int qb = (32 * Bn - 2 * t - 1) >> 2;
      pA0 = DrowA[qclamp(qa + 0)]; pA1 = DrowA[qclamp(qa + 1)];
      pA2 = DrowA[qclamp(qa + 2)]; pA3 = DrowA[qclamp(qa + 3)];
      pA4 = DrowA[qclamp(qa + 4)]; pA5 = DrowA[qclamp(qa + 5)];
      pA6 = DrowA[qclamp(qa + 6)]; pA7 = DrowA[qclamp(qa + 7)];
      pA8 = DrowA[qclamp(qa + 8)];
      pB0 = DrowB[qclamp(qb + 0)]; pB1 = DrowB[qclamp(qb + 1)];
      pB2 = DrowB[qclamp(qb + 2)]; pB3 = DrowB[qclamp(qb + 3)];
      pB4 = DrowB[qclamp(qb + 4)]; pB5 = DrowB[qclamp(qb + 5)];
      pB6 = DrowB[qclamp(qb + 6)]; pB7 = DrowB[qclamp(qb + 7)];
      pB8 = DrowB[qclamp(qb + 8)];
    }

    if (B >= Bl && B <= Bh) {
      const int d0 = 2 + 32 * B;
      const int c0A = 32 * B - 2 * t;   // even; cell A col at kk=0

      // ---- neighbor boundary preload (row 128w-1 = wave w-1 lane63 cell B)
      float4 n0, n1, n2, n3, n4, n5, n6, n7, n8, n9, n10, n11, n12, n13, n14, n15;
      if (w > 0) {
        const float4* ep = (const float4*)&edge[w - 1][OFF + (32 * B - 128 * w)];
        n0 = ep[0];  n1 = ep[1];  n2 = ep[2];  n3 = ep[3];
        n4 = ep[4];  n5 = ep[5];  n6 = ep[6];  n7 = ep[7];
        n8 = ep[8];  n9 = ep[9];  n10 = ep[10]; n11 = ep[11];
        n12 = ep[12]; n13 = ep[13]; n14 = ep[14]; n15 = ep[15];
      } else {
        const float4 z = make_float4(0.f, 0.f, 0.f, 0.f);
        n0 = n1 = n2 = n3 = n4 = n5 = n6 = n7 = z;
        n8 = n9 = n10 = n11 = n12 = n13 = n14 = n15 = z;
      }

      // ---- funnels: gA[e]=D[rowA][c0A+e], gB[e]=D[rowB][c0A-1+e]
      const bool s2a = (c0A & 2) != 0;          // c0A even: shift 0 or 2
      const bool s2b = ((c0A - 1) & 2) != 0;    // c0B odd: shift 1 or 3
      const float
        a0 = rA0.x, a1 = rA0.y, a2 = rA0.z, a3 = rA0.w,
        a4 = rA1.x, a5 = rA1.y, a6 = rA1.z, a7 = rA1.w,
        a8 = rA2.x, a9 = rA2.y, a10 = rA2.z, a11 = rA2.w,
        a12 = rA3.x, a13 = rA3.y, a14 = rA3.z, a15 = rA3.w,
        a16 = rA4.x, a17 = rA4.y, a18 = rA4.z, a19 = rA4.w,
        a20 = rA5.x, a21 = rA5.y, a22 = rA5.z, a23 = rA5.w,
        a24 = rA6.x, a25 = rA6.y, a26 = rA6.z, a27 = rA6.w,
        a28 = rA7.x, a29 = rA7.y, a30 = rA7.z, a31 = rA7.w,
        a32 = rA8.x, a33 = rA8.y;
      const float
        gA0  = s2a ? a2  : a0,  gA1  = s2a ? a3  : a1,  gA2  = s2a ? a4  : a2,
        gA3  = s2a ? a5  : a3,  gA4  = s2a ? a6  : a4,  gA5  = s2a ? a7  : a5,
        gA6  = s2a ? a8  : a6,  gA7  = s2a ? a9  : a7,  gA8  = s2a ? a10 : a8,
        gA9  = s2a ? a11 : a9,  gA10 = s2a ? a12 : a10, gA11 = s2a ? a13 : a11,
        gA12 = s2a ? a14 : a12, gA13 = s2a ? a15 : a13, gA14 = s2a ? a16 : a14,
        gA15 = s2a ? a17 : a15, gA16 = s2a ? a18 : a16, gA17 = s2a ? a19 : a17,
        gA18 = s2a ? a20 : a18, gA19 = s2a ? a21 : a19, gA20 = s2a ? a22 : a20,
        gA21 = s2a ? a23 : a21, gA22 = s2a ? a24 : a22, gA23 = s2a ? a25 : a23,
        gA24 = s2a ? a26 : a24, gA25 = s2a ? a27 : a25, gA26 = s2a ? a28 : a26,
        gA27 = s2a ? a29 : a27, gA28 = s2a ? a30 : a28, gA29 = s2a ? a31 : a29,
        gA30 = s2a ? a32 : a30, gA31 = s2a ? a33 : a31;
      const float
        b1 = rB0.y, b2 = rB0.z, b3 = rB0.w,
        b4 = rB1.x, b5 = rB1.y, b6 = rB1.z, b7 = rB1.w,
        b8 = rB2.x, b9 = rB2.y, b10 = rB2.z, b11 = rB2.w,
        b12 = rB3.x, b13 = rB3.y, b14 = rB3.z, b15 = rB3.w,
        b16 = rB4.x, b17 = rB4.y, b18 = rB4.z, b19 = rB4.w,
        b20 = rB5.x, b21 = rB5.y, b22 = rB5.z, b23 = rB5.w,
        b24 = rB6.x, b25 = rB6.y, b26 = rB6.z, b27 = rB6.w,
        b28 = rB7.x, b29 = rB7.y, b30 = rB7.z, b31 = rB7.w,
        b32 = rB8.x, b33 = rB8.y, b34 = rB8.z;
      const float
        gB0  = s2b ? b3  : b1,  gB1  = s2b ? b4  : b2,  gB2  = s2b ? b5  : b3,
        gB3  = s2b ? b6  : b4,  gB4  = s2b ? b7  : b5,  gB5  = s2b ? b8  : b6,
        gB6  = s2b ? b9  : b7,  gB7  = s2b ? b10 : b8,  gB8  = s2b ? b11 : b9,
        gB9  = s2b ? b12 : b10, gB10 = s2b ? b13 : b11, gB11 = s2b ? b14 : b12,
        gB12 = s2b ? b15 : b13, gB13 = s2b ? b16 : b14, gB14 = s2b ? b17 : b15,
        gB15 = s2b ? b18 : b16, gB16 = s2b ? b19 : b17, gB17 = s2b ? b20 : b18,
        gB18 = s2b ? b21 : b19, gB19 = s2b ? b22 : b20, gB20 = s2b ? b23 : b21,
        gB21 = s2b ? b24 : b22, gB22 = s2b ? b25 : b23, gB23 = s2b ? b26 : b24,
        gB24 = s2b ? b27 : b25, gB25 = s2b ? b28 : b26, gB26 = s2b ? b29 : b27,
        gB27 = s2b ? b30 : b28, gB28 = s2b ? b31 : b29, gB29 = s2b ? b32 : b30,
        gB30 = s2b ? b33 : b31, gB31 = s2b ? b34 : b32;

      float2* eput = &edge[w][OFF + c0A - 1];   // write-once publish (cell B)

#define STEP(kk, GA, GB, NE, ND)                                              \
      {                                                                       \
        const bool vA = ((unsigned)(c0A + (kk))) < 512u;                      \
        const bool vB = ((unsigned)(c0A + (kk) - 1)) < 512u;                  \
        float sE = lane_shr1(eB);                                             \
        float sD = lane_shr1(dB);                                             \
        sE = l0 ? (NE) : sE;                                                  \
        sD = l0 ? (ND) : sD;                                                  \
        const float dLA = (GA) * NL2E;                                        \
        const float dLB = (GB) * NL2E;                                        \
        const float sumA = (eN2A + eA) + sE;                                  \
        const float invA = __builtin_amdgcn_rcpf(sumA);                       \
        const float numA = fmaf(eN2A, dN2A, fmaf(sE, sD, eA * dA));           \
        const float rrA = fmaf(invA, numA, dLA);                              \
        float newEA = __builtin_amdgcn_exp2f(rrA);                            \
        newEA = vA ? newEA : 0.f;                                             \
        const float sumB = (eN2B + eB) + eA;                                  \
        const float invB = __builtin_amdgcn_rcpf(sumB);                       \
        const float numB = fmaf(eN2B, dN2B, fmaf(eA, dA, eB * dB));           \
        const float rrB = fmaf(invB, numB, dLB);                              \
        float newEB = __builtin_amdgcn_exp2f(rrB);                            \
        newEB = vB ? newEB : 0.f;                                             \
        if (d0 + (kk) == NM && t == 255) {                                    \
          out[b] = rrB * NLN2;                                                \
          out[BATCH + b] = sgA + invB * (eN2B * sg0 + eA * sg1 + eB * sg2);   \
        }                                                                     \
        eN2A = sE; dN2A = sD;                                                 \
        eN2B = eA; dN2B = dA;                                                 \
        eA = newEA; dA = dLA;                                                 \
        eB = newEB; dB = dLB;                                                 \
        eput[kk] = make_float2(newEB, dLB);                                   \
      }
#define STEP2(j, GA0, GA1, GB0, GB1)                                          \
      STEP(2 * (j), GA0, GB0, n##j.x, n##j.y)                                 \
      STEP(2 * (j) + 1, GA1, GB1, n##j.z, n##j.w)

      STEP2(0,  gA0,  gA1,  gB0,  gB1)   STEP2(1,  gA2,  gA3,  gB2,  gB3)
      STEP2(2,  gA4,  gA5,  gB4,  gB5)   STEP2(3,  gA6,  gA7,  gB6,  gB7)
      STEP2(4,  gA8,  gA9,  gB8,  gB9)   STEP2(5,  gA10, gA11, gB10, gB11)
      STEP2(6,  gA12, gA13, gB12, gB13)  STEP2(7,  gA14, gA15, gB14, gB15)
      STEP2(8,  gA16, gA17, gB16, gB17)  STEP2(9,  gA18, gA19, gB18, gB19)
      STEP2(10, gA20, gA21, gB20, gB21)  STEP2(11, gA22, gA23, gB22, gB23)
      STEP2(12, gA24, gA25, gB24, gB25)  STEP2(13, gA26, gA27, gB26, gB27)
      STEP2(14, gA28, gA29, gB28, gB29)  STEP2(15, gA30, gA31, gB30, gB31)
#undef STEP2
#undef STEP
    }

    if (dopre) {
      rA0 = pA0; rA1 = pA1; rA2 = pA2; rA3 = pA3; rA4 = pA4;
      rA5 = pA5; rA6 = pA6; rA7 = pA7; rA8 = pA8;
      rB0 = pB0; rB1 = pB1; rB2 = pB2; rB3 = pB3; rB4 = pB4;
      rB5 = pB5; rB6 = pB6; rB7 = pB7; rB8 = pB8;
    }
    __syncthreads();
  }
}

extern "C" void kernel_launch(void* const* d_in, const int* in_sizes, int n_in,
                              void* d_out, int out_size, void* d_ws, size_t ws_size,
                              hipStream_t stream) {
  const float* D   = (const float*)d_in[0];
  const float* Sig = (const float*)d_in[1];
  float* out = (float*)d_out;
  softdtw_fwd<<<dim3(BATCH), dim3(256), 0, stream>>>(D, Sig, out);
}

// Round 10
// 179.967 us; speedup vs baseline: 1.1944x; 1.1944x over previous
//
#include <hip/hip_runtime.h>

// uDTW forward DP, R9 = R7 structure (best measured: 512 thr, 8 waves, K=32,
// 39 phases, reg double-buffer D prefetch, write-once halo publish) with a
// shaved step body:
//  - boundary select folded into DPP: update_dpp(old=NE, src, wave_shr:1,
//    bound_ctrl=false) -> lane0 keeps old (neighbor vals are wave-uniform
//    VGPRs) => both per-step l0 cndmasks gone, chain shorter.
//  - validity masked in log2 domain (ddLm = valid ? ddL : -1e30) BEFORE the
//    exp2, with sum += 1e-30 so rcp never sees 0 (valid sums >= e^-2: this
//    uDTW's R = D + convex comb of D's, always in [0,2]) => no post-exp2
//    cndmask, no NaN.
//  - carry/publish raw scaled D (consumers multiply by masked-zero E).
// R8 lesson: keep 8B-stride b64 publishes (conflict-free; 16B stride gave
// 327k bank-conflict cycles) and 2 waves/SIMD (latency hiding).

constexpr int N = 512;
constexpr int M = 512;
constexpr int BATCH = 32;
constexpr int NM = N + M;                  // 1024; diags d = 2..NM
constexpr int K = 32;                      // diagonals per burst
constexpr int NB = 32;                     // bursts cover d = 2..1025
constexpr int PHASES = NB + 7;             // 39
constexpr float NL2E = -1.4426950408889634f;   // -log2(e)
constexpr float NLN2 = -0.6931471805599453f;   // -ln(2)
constexpr float EPS  = 1e-30f;

__device__ __forceinline__ float lane_shr1_or(float oldv, float x) {
  // lane n gets lane n-1's x; lane 0 keeps oldv (bound_ctrl=false).
  return __int_as_float(__builtin_amdgcn_update_dpp(
      __float_as_int(oldv), __float_as_int(x), 0x138, 0xf, 0xf, false));
}
__device__ __forceinline__ int qclamp(int q) {
  return q < 0 ? 0 : (q > 127 ? 127 : q);
}

__global__ __launch_bounds__(512, 2)
void softdtw_fwd(const float* __restrict__ D,
                 const float* __restrict__ Sig,
                 float* __restrict__ out) {
  const int b = blockIdx.x;
  const int t = threadIdx.x;           // row r = t, cell i = t+1
  const int w = t >> 6;                // wave 0..7
  const float4* Drow4 = (const float4*)(D + ((size_t)b * N + t) * M);

  // edge[w][64 + c] = (exp(-R), NL2E*Ddiag) of row 64w+63 at column c.
  __shared__ float2 edge[8][640];
  for (int idx = t; idx < 8 * 640; idx += 512)
    ((float2*)edge)[idx] = make_float2(0.f, 0.f);

  // carried state: own cell at d-1, neighbor (i-1) at d-2 (D pre-scaled)
  float eSelf = 0.f, dSelfL = 0.f;
  float eN2 = (t == 0) ? 1.f : 0.f, dN2L = 0.f;   // R[0,0]=0 -> e=1

  // Sig contributes only via 4 elements at the final cell
  float sgA = 0.f, sg0 = 0.f, sg1 = 0.f, sg2 = 0.f;
  if (t == N - 1) {
    const float* Sb = Sig + (size_t)b * N * M;
    sgA = Sb[(size_t)(N - 1) * M + (M - 1)];
    sg0 = Sb[(size_t)(N - 2) * M + (M - 2)];
    sg1 = Sb[(size_t)(N - 2) * M + (M - 1)];
    sg2 = Sb[(size_t)(N - 1) * M + (M - 2)];
  }

  const int Bl = 2 * w, Bh = 2 * w + 17;   // active bursts for this wave

  // current-burst D window: 9 quads covering floats [4*((32B-t)>>2), +36)
  float4 r0, r1, r2, r3, r4, r5, r6, r7, r8;
  {
    const int q = (32 * Bl - t) >> 2;
    r0 = Drow4[qclamp(q + 0)]; r1 = Drow4[qclamp(q + 1)];
    r2 = Drow4[qclamp(q + 2)]; r3 = Drow4[qclamp(q + 3)];
    r4 = Drow4[qclamp(q + 4)]; r5 = Drow4[qclamp(q + 5)];
    r6 = Drow4[qclamp(q + 6)]; r7 = Drow4[qclamp(q + 7)];
    r8 = Drow4[qclamp(q + 8)];
  }
  __syncthreads();

  for (int p = 0; p < PHASES; ++p) {
    const int B = p - w;
    const int nB = B + 1;
    const bool dopre = (nB >= Bl) && (nB <= Bh);   // wave-uniform

    // ---- prefetch next burst's D quads (consumed after the barrier)
    float4 p0, p1, p2, p3, p4, p5, p6, p7, p8;
    if (dopre) {
      const int q = (32 * nB - t) >> 2;
      p0 = Drow4[qclamp(q + 0)]; p1 = Drow4[qclamp(q + 1)];
      p2 = Drow4[qclamp(q + 2)]; p3 = Drow4[qclamp(q + 3)];
      p4 = Drow4[qclamp(q + 4)]; p5 = Drow4[qclamp(q + 5)];
      p6 = Drow4[qclamp(q + 6)]; p7 = Drow4[qclamp(q + 7)];
      p8 = Drow4[qclamp(q + 8)];
    }

    if (B >= Bl && B <= Bh) {
      const int d0 = 2 + B * K;
      const int c0 = d0 - t - 2;       // = 32B - t; in [-63, 544]

      // ---- neighbor boundary preload: 16 float4 (32 (E,D) pairs)
      float4 n0, n1, n2, n3, n4, n5, n6, n7, n8, n9, n10, n11, n12, n13, n14, n15;
      if (w > 0) {
        const float4* ep = (const float4*)&edge[w - 1][64 + (d0 - 64 * w - 2)];
        n0 = ep[0];  n1 = ep[1];  n2 = ep[2];  n3 = ep[3];
        n4 = ep[4];  n5 = ep[5];  n6 = ep[6];  n7 = ep[7];
        n8 = ep[8];  n9 = ep[9];  n10 = ep[10]; n11 = ep[11];
        n12 = ep[12]; n13 = ep[13]; n14 = ep[14]; n15 = ep[15];
      } else {
        const float4 z = make_float4(0.f, 0.f, 0.f, 0.f);
        n0 = n1 = n2 = n3 = n4 = n5 = n6 = n7 = z;
        n8 = n9 = n10 = n11 = n12 = n13 = n14 = n15 = z;
      }

      // ---- funnel align by s = c0 & 3: g_e = D[c0 + e], e in [0,32)
      const int s = c0 & 3;
      const bool s2 = (s & 2) != 0, s1b = (s & 1) != 0;
      const float
        f0 = r0.x, f1 = r0.y, f2 = r0.z, f3 = r0.w,
        f4 = r1.x, f5 = r1.y, f6 = r1.z, f7 = r1.w,
        f8 = r2.x, f9 = r2.y, f10 = r2.z, f11 = r2.w,
        f12 = r3.x, f13 = r3.y, f14 = r3.z, f15 = r3.w,
        f16 = r4.x, f17 = r4.y, f18 = r4.z, f19 = r4.w,
        f20 = r5.x, f21 = r5.y, f22 = r5.z, f23 = r5.w,
        f24 = r6.x, f25 = r6.y, f26 = r6.z, f27 = r6.w,
        f28 = r7.x, f29 = r7.y, f30 = r7.z, f31 = r7.w,
        f32 = r8.x, f33 = r8.y, f34 = r8.z, f35 = r8.w;
      const float
        x0  = s2 ? f2  : f0,  x1  = s2 ? f3  : f1,  x2  = s2 ? f4  : f2,
        x3  = s2 ? f5  : f3,  x4  = s2 ? f6  : f4,  x5  = s2 ? f7  : f5,
        x6  = s2 ? f8  : f6,  x7  = s2 ? f9  : f7,  x8  = s2 ? f10 : f8,
        x9  = s2 ? f11 : f9,  x10 = s2 ? f12 : f10, x11 = s2 ? f13 : f11,
        x12 = s2 ? f14 : f12, x13 = s2 ? f15 : f13, x14 = s2 ? f16 : f14,
        x15 = s2 ? f17 : f15, x16 = s2 ? f18 : f16, x17 = s2 ? f19 : f17,
        x18 = s2 ? f20 : f18, x19 = s2 ? f21 : f19, x20 = s2 ? f22 : f20,
        x21 = s2 ? f23 : f21, x22 = s2 ? f24 : f22, x23 = s2 ? f25 : f23,
        x24 = s2 ? f26 : f24, x25 = s2 ? f27 : f25, x26 = s2 ? f28 : f26,
        x27 = s2 ? f29 : f27, x28 = s2 ? f30 : f28, x29 = s2 ? f31 : f29,
        x30 = s2 ? f32 : f30, x31 = s2 ? f33 : f31, x32 = s2 ? f34 : f32;
      const float
        g0  = s1b ? x1  : x0,  g1  = s1b ? x2  : x1,  g2  = s1b ? x3  : x2,
        g3  = s1b ? x4  : x3,  g4  = s1b ? x5  : x4,  g5  = s1b ? x6  : x5,
        g6  = s1b ? x7  : x6,  g7  = s1b ? x8  : x7,  g8  = s1b ? x9  : x8,
        g9  = s1b ? x10 : x9,  g10 = s1b ? x11 : x10, g11 = s1b ? x12 : x11,
        g12 = s1b ? x13 : x12, g13 = s1b ? x14 : x13, g14 = s1b ? x15 : x14,
        g15 = s1b ? x16 : x15, g16 = s1b ? x17 : x16, g17 = s1b ? x18 : x17,
        g18 = s1b ? x19 : x18, g19 = s1b ? x20 : x19, g20 = s1b ? x21 : x20,
        g21 = s1b ? x22 : x21, g22 = s1b ? x23 : x22, g23 = s1b ? x24 : x23,
        g24 = s1b ? x25 : x24, g25 = s1b ? x26 : x25, g26 = s1b ? x27 : x26,
        g27 = s1b ? x28 : x27, g28 = s1b ? x29 : x28, g29 = s1b ? x30 : x29,
        g30 = s1b ? x31 : x30, g31 = s1b ? x32 : x31;

      float2* eput = &edge[w][64 + c0];   // write-once publish (8B stride)

#define STEP(kk, GK, NE, ND)                                                   \
      {                                                                        \
        const int c = c0 + (kk);                                               \
        const bool valid = ((unsigned)c) < 512u;                               \
        const float ddL = (GK) * NL2E;                                         \
        const float ddLm = valid ? ddL : -1e30f;                               \
        const float sE = lane_shr1_or((NE), eSelf);                            \
        const float sD = lane_shr1_or((ND), dSelfL);                           \
        const float e0 = eN2, e2 = eSelf;                                      \
        const float s02 = (e0 + e2) + EPS;                                     \
        const float sum = s02 + sE;                                            \
        const float inv = __builtin_amdgcn_rcpf(sum);                          \
        const float numL = fmaf(e0, dN2L, fmaf(sE, sD, e2 * dSelfL));          \
        const float rr = fmaf(inv, numL, ddLm);                                \
        const float newE = __builtin_amdgcn_exp2f(rr);                         \
        if (d0 + (kk) == NM && t == N - 1) {                                   \
          out[b] = rr * NLN2;                                                  \
          out[BATCH + b] = sgA + inv * (e0 * sg0 + sE * sg1 + e2 * sg2);       \
        }                                                                      \
        eN2 = sE; dN2L = sD;                                                   \
        eSelf = newE; dSelfL = ddL;                                            \
        eput[kk] = make_float2(newE, ddL);                                     \
      }
#define STEP2(m, GA, GB)                                                       \
      STEP(2 * m, GA, n##m.x, n##m.y)                                          \
      STEP(2 * m + 1, GB, n##m.z, n##m.w)

      STEP2(0,  g0,  g1)   STEP2(1,  g2,  g3)
      STEP2(2,  g4,  g5)   STEP2(3,  g6,  g7)
      STEP2(4,  g8,  g9)   STEP2(5,  g10, g11)
      STEP2(6,  g12, g13)  STEP2(7,  g14, g15)
      STEP2(8,  g16, g17)  STEP2(9,  g18, g19)
      STEP2(10, g20, g21)  STEP2(11, g22, g23)
      STEP2(12, g24, g25)  STEP2(13, g26, g27)
      STEP2(14, g28, g29)  STEP2(15, g30, g31)
#undef STEP2
#undef STEP
    }

    // rotate in the prefetched window (waitcnt lands here, ~600 inst later)
    if (dopre) {
      r0 = p0; r1 = p1; r2 = p2; r3 = p3; r4 = p4;
      r5 = p5; r6 = p6; r7 = p7; r8 = p8;
    }
    __syncthreads();
  }
}

extern "C" void kernel_launch(void* const* d_in, const int* in_sizes, int n_in,
                              void* d_out, int out_size, void* d_ws, size_t ws_size,
                              hipStream_t stream) {
  const float* D   = (const float*)d_in[0];
  const float* Sig = (const float*)d_in[1];
  float* out = (float*)d_out;
  softdtw_fwd<<<dim3(BATCH), dim3(512), 0, stream>>>(D, Sig, out);
}